// Round 6
// baseline (96.457 us; speedup 1.0000x reference)
//
#include <hip/hip_runtime.h>
#include <cstdint>
#include <cstddef>

// Fused prefix-LM self-attention, B=8192, S=64, D=32, H=4, DH=8.
// Block = 128 thr = 2 waves = 1 batch; wave w owns heads {2w,2w+1}.
// bf16 MFMA 16x16x32 end-to-end. Each wave computes its own 16 q/k/v dims
// (per-lane vector weight loads), stages K/V^T into disjoint regions of
// shared LDS arrays (72B rows -> conflict-free), keeps Q^T in registers.
// P redistributed through a per-wave single-buffered LDS slice (DS pipe
// is in-order per wave). Streaming softmax (no max subtraction, |score|<~2),
// col-sums via 2x shfl_xor. Final Y = sum of both waves' head-partials,
// exchanged through reclaimed LDS (2 __syncthreads total).
#define NB 8192

typedef __attribute__((ext_vector_type(8))) short short8;
typedef __attribute__((ext_vector_type(4))) float f32x4;

union S8U { short8 s; unsigned u[4]; uint4 v; };

static __device__ __forceinline__ unsigned pk2(float a, float b) {
    unsigned short ua = __builtin_bit_cast(unsigned short, (__bf16)a);
    unsigned short ub = __builtin_bit_cast(unsigned short, (__bf16)b);
    return (unsigned)ua | ((unsigned)ub << 16);
}

#define MFMA __builtin_amdgcn_mfma_f32_16x16x32_bf16
#define BPERM __builtin_amdgcn_ds_bpermute
// compiler-only fence: pins in-wave LDS write->read program order
#define LDSFENCE() asm volatile("" ::: "memory")

__global__ __launch_bounds__(128, 6) void fused_attn_mfma(
    const float* __restrict__ x,
    const int*   __restrict__ aatt,
    const float* __restrict__ Wq, const float* __restrict__ bq,
    const float* __restrict__ Wk, const float* __restrict__ bk,
    const float* __restrict__ Wv, const float* __restrict__ bv,
    const float* __restrict__ Wp, const float* __restrict__ bp,
    float* __restrict__ out)
{
    __shared__ __align__(16) short klds[64][36];   // K[seq][dim], 72B rows (4608B)
    __shared__ __align__(16) short vbt[32][72];    // V^T[dim][seq], 144B rows (4608B)
    __shared__ __align__(16) short psl[2][16][40]; // per-wave P slice (2560B)

    const int tid  = threadIdx.x;
    const int w    = tid >> 6;          // wave: heads {2w, 2w+1}, dims 16w..16w+15
    const int lane = tid & 63;
    const int q4   = lane >> 4;
    const int l15  = lane & 15;
    const int b    = blockIdx.x;

    const int aab      = aatt[b];
    const unsigned bmask = (q4 == 0) ? 0xFFFFFFFFu : 0u;

    // allowed(j) == j <= max(i, aab-1); j = (compile-time C) + q4*4
    int cmpv[4];
#pragma unroll
    for (int it = 0; it < 4; ++it) cmpv[it] = max(l15 + 16*it, aab - 1) - q4*4;

    // ---- X fragments: row = tile*16+l15, k = q4*8+e ----
    short8 xa[4];
    const float* xb = x + (size_t)b * 64 * 32;
#pragma unroll
    for (int nt = 0; nt < 4; ++nt) {
        const float* p = xb + (nt*16 + l15)*32 + q4*8;
        float4 u0 = *(const float4*)p;
        float4 u1 = *(const float4*)(p + 4);
        S8U t;
        t.u[0] = pk2(u0.x, u0.y); t.u[1] = pk2(u0.z, u0.w);
        t.u[2] = pk2(u1.x, u1.y); t.u[3] = pk2(u1.z, u1.w);
        xa[nt] = t.s;
    }

    auto wrow = [&](const float* W, int row) -> short8 {
        const float* p = W + row*32 + q4*8;
        float4 u0 = *(const float4*)p;
        float4 u1 = *(const float4*)(p + 4);
        S8U t;
        t.u[0] = pk2(u0.x, u0.y); t.u[1] = pk2(u0.z, u0.w);
        t.u[2] = pk2(u1.x, u1.y); t.u[3] = pk2(u1.z, u1.w);
        return t.s;
    };

    const float escale = 0.35355339059327373f * 1.4426950408889634f; // 1/sqrt(8)*log2(e)

    // ---- Q^T (this wave's 16 dims) -> registers, bias+scale in f32 ----
    unsigned qpk01[4], qpk23[4];
    {
        short8 wa = wrow(Wq, 16*w + l15);
        float4 b4 = *(const float4*)(bq + 16*w + q4*4);
#pragma unroll
        for (int nt = 0; nt < 4; ++nt) {
            f32x4 acc = {0.f,0.f,0.f,0.f};
            acc = MFMA(wa, xa[nt], acc, 0,0,0);
            qpk01[nt] = pk2((acc[0]+b4.x)*escale, (acc[1]+b4.y)*escale);
            qpk23[nt] = pk2((acc[2]+b4.z)*escale, (acc[3]+b4.w)*escale);
        }
    }
    // ---- K^T (this wave's 16 dims) -> klds cols 16w.. ----
    {
        short8 wa = wrow(Wk, 16*w + l15);
        float4 b4 = *(const float4*)(bk + 16*w + q4*4);
#pragma unroll
        for (int nt = 0; nt < 4; ++nt) {
            f32x4 acc = {0.f,0.f,0.f,0.f};
            acc = MFMA(wa, xa[nt], acc, 0,0,0);
            uint2 w2;
            w2.x = pk2(acc[0]+b4.x, acc[1]+b4.y);
            w2.y = pk2(acc[2]+b4.z, acc[3]+b4.w);
            *(uint2*)&klds[nt*16 + l15][16*w + q4*4] = w2;
        }
    }
    // ---- V (this wave's 16 dims) -> vbt rows 16w.. (V transposed) ----
    {
        short8 wv = wrow(Wv, 16*w + l15);
        const float bvv = bv[16*w + l15];
#pragma unroll
        for (int mt = 0; mt < 4; ++mt) {
            f32x4 acc = {0.f,0.f,0.f,0.f};
            acc = MFMA(xa[mt], wv, acc, 0,0,0);
            uint2 w2;
            w2.x = pk2(acc[0]+bvv, acc[1]+bvv);
            w2.y = pk2(acc[2]+bvv, acc[3]+bvv);
            *(uint2*)&vbt[16*w + l15][mt*16 + q4*4] = w2;
        }
    }
    LDSFENCE();   // wave reads only its own staging regions -> no barrier

    // ---- head loop (2 heads per wave) ----
    f32x4 yacc[4][2];
#pragma unroll
    for (int mt = 0; mt < 4; ++mt)
#pragma unroll
        for (int nt = 0; nt < 2; ++nt) yacc[mt][nt] = (f32x4){0.f,0.f,0.f,0.f};

#pragma unroll
    for (int hl = 0; hl < 2; ++hl) {
        const int idxA = (32*hl + l15) * 4;        // lane (q4=2hl,   l15)
        const int idxB = idxA + 64;                // lane (q4=2hl+1, l15)

        // Q B-frags: zero k>=8 via bmask
        short8 sqb[4];
#pragma unroll
        for (int it = 0; it < 4; ++it) {
            S8U t;
            t.u[0] = (unsigned)BPERM(idxA, (int)qpk01[it]) & bmask;
            t.u[1] = (unsigned)BPERM(idxA, (int)qpk23[it]) & bmask;
            t.u[2] = (unsigned)BPERM(idxB, (int)qpk01[it]) & bmask;
            t.u[3] = (unsigned)BPERM(idxB, (int)qpk23[it]) & bmask;
            sqb[it] = t.s;
        }
        // Wp head-slice B-frags (head h = 2w+hl), zero k>=8
        short8 wpb[2];
#pragma unroll
        for (int nt = 0; nt < 2; ++nt) {
            const float* p = Wp + (nt*16 + l15)*32 + 16*w + 8*hl;
            float4 u0 = *(const float4*)p;
            float4 u1 = *(const float4*)(p + 4);
            S8U t;
            t.u[0] = pk2(u0.x,u0.y) & bmask;
            t.u[1] = pk2(u0.z,u0.w) & bmask;
            t.u[2] = pk2(u1.x,u1.y) & bmask;
            t.u[3] = pk2(u1.z,u1.w) & bmask;
            wpb[nt] = t.s;
        }

        float csum[4] = {0.f,0.f,0.f,0.f};
        f32x4 oacch[4];
#pragma unroll
        for (int it = 0; it < 4; ++it) oacch[it] = (f32x4){0.f,0.f,0.f,0.f};

#pragma unroll
        for (int jb = 0; jb < 2; ++jb) {
            // K A-frags: q4-uniform broadcast rows; k>=8 garbage killed by B zero
            short8 ska[2];
#pragma unroll
            for (int jt = 0; jt < 2; ++jt) {
                S8U t; t.v = *(const uint4*)&klds[jb*32 + jt*16 + l15][16*w + 8*hl];
                ska[jt] = t.s;
            }
            // V^T A-frag for this head & j-half
            S8U av; av.v = *(const uint4*)&vbt[16*w + 8*hl + (l15 & 7)][jb*32 + q4*8];

#pragma unroll
            for (int it = 0; it < 4; ++it) {
#pragma unroll
                for (int jt = 0; jt < 2; ++jt) {
                    f32x4 sacc = {0.f,0.f,0.f,0.f};
                    sacc = MFMA(ska[jt], sqb[it], sacc, 0,0,0);
                    float e[4];
#pragma unroll
                    for (int r = 0; r < 4; ++r) {
                        float ee = __builtin_amdgcn_exp2f(sacc[r]);
                        e[r] = (jb*32 + jt*16 + r <= cmpv[it]) ? ee : 0.0f;
                    }
                    csum[it] += (e[0]+e[1]) + (e[2]+e[3]);
                    uint2 pw; pw.x = pk2(e[0], e[1]); pw.y = pk2(e[2], e[3]);
                    *(uint2*)&psl[w][l15][jt*16 + q4*4] = pw;
                }
                LDSFENCE();
                S8U pb; pb.v = *(const uint4*)&psl[w][l15][q4*8];
                oacch[it] = MFMA(av.s, pb.s, oacch[it], 0,0,0);
                LDSFENCE();
            }
        }

        // column sums + normalize
        float inv[4];
#pragma unroll
        for (int it = 0; it < 4; ++it) {
            float a = csum[it];
            a += __shfl_xor(a, 16, 64);
            a += __shfl_xor(a, 32, 64);
            inv[it] = 1.0f / a;
        }
        unsigned opk01[4], opk23[4];
#pragma unroll
        for (int it = 0; it < 4; ++it) {
            opk01[it] = pk2(oacch[it][0]*inv[it], oacch[it][1]*inv[it]);
            opk23[it] = pk2(oacch[it][2]*inv[it], oacch[it][3]*inv[it]);
        }
        // out-projection partial: Y += O_head @ Wp_head^T
        const int idx0 = l15 * 4;
        const int idx1 = idx0 + 64;
#pragma unroll
        for (int mtile = 0; mtile < 4; ++mtile) {
            S8U t;
            t.u[0] = (unsigned)BPERM(idx0, (int)opk01[mtile]);
            t.u[1] = (unsigned)BPERM(idx0, (int)opk23[mtile]);
            t.u[2] = (unsigned)BPERM(idx1, (int)opk01[mtile]);
            t.u[3] = (unsigned)BPERM(idx1, (int)opk23[mtile]);
#pragma unroll
            for (int nt = 0; nt < 2; ++nt)
                yacc[mtile][nt] = MFMA(t.s, wpb[nt], yacc[mtile][nt], 0,0,0);
        }
    }

    // ---- cross-wave reduction of Y partials through reclaimed LDS ----
    __syncthreads();   // all klds/vbt reads complete
    float* scrA = (float*)&klds[0][0];   // wave0 writes here (4096B used)
    float* scrB = (float*)&vbt[0][0];    // wave1 writes here
    if (w == 0) {
#pragma unroll
        for (int mtl = 0; mtl < 2; ++mtl)
#pragma unroll
            for (int nt = 0; nt < 2; ++nt)
                *(f32x4*)&scrA[((mtl*2 + nt)*64 + lane)*4] = yacc[2 + mtl][nt];
    } else {
#pragma unroll
        for (int mtl = 0; mtl < 2; ++mtl)
#pragma unroll
            for (int nt = 0; nt < 2; ++nt)
                *(f32x4*)&scrB[((mtl*2 + nt)*64 + lane)*4] = yacc[mtl][nt];
    }
    __syncthreads();

    const float bpv[2] = { bp[l15], bp[16 + l15] };
    float* ob = out + (size_t)b * 64 * 32;
    if (w == 0) {      // rows 0..31  (mtiles 0,1), partner partial from scrB
#pragma unroll
        for (int mtl = 0; mtl < 2; ++mtl)
#pragma unroll
            for (int nt = 0; nt < 2; ++nt) {
                f32x4 o = *(const f32x4*)&scrB[((mtl*2 + nt)*64 + lane)*4];
#pragma unroll
                for (int r = 0; r < 4; ++r)
                    ob[(mtl*16 + q4*4 + r)*32 + nt*16 + l15] =
                        yacc[mtl][nt][r] + o[r] + bpv[nt];
            }
    } else {           // rows 32..63 (mtiles 2,3), partner partial from scrA
#pragma unroll
        for (int mtl = 0; mtl < 2; ++mtl)
#pragma unroll
            for (int nt = 0; nt < 2; ++nt) {
                f32x4 o = *(const f32x4*)&scrA[((mtl*2 + nt)*64 + lane)*4];
#pragma unroll
                for (int r = 0; r < 4; ++r)
                    ob[((2 + mtl)*16 + q4*4 + r)*32 + nt*16 + l15] =
                        yacc[2 + mtl][nt][r] + o[r] + bpv[nt];
            }
    }
}

extern "C" void kernel_launch(void* const* d_in, const int* in_sizes, int n_in,
                              void* d_out, int out_size, void* d_ws, size_t ws_size,
                              hipStream_t stream) {
    const float* x  = (const float*)d_in[0];
    const int*   aa = (const int*)d_in[1];
    const float* Wq = (const float*)d_in[2];
    const float* bq = (const float*)d_in[3];
    const float* Wk = (const float*)d_in[4];
    const float* bk = (const float*)d_in[5];
    const float* Wv = (const float*)d_in[6];
    const float* bv = (const float*)d_in[7];
    const float* Wp = (const float*)d_in[8];
    const float* bp = (const float*)d_in[9];
    float* out = (float*)d_out;

    dim3 grid(NB), block(128);
    hipLaunchKernelGGL(fused_attn_mfma, grid, block, 0, stream,
                       x, aa, Wq, bq, Wk, bk, Wv, bv, Wp, bp, out);
}

// Round 7
// 80.093 us; speedup vs baseline: 1.2043x; 1.2043x over previous
//
#include <hip/hip_runtime.h>
#include <cstdint>
#include <cstddef>

// Fused prefix-LM self-attention, B=8192, S=64, D=32, H=4, DH=8.
// Block = 128 thr = 2 waves = 1 batch; wave w owns heads {2w,2w+1}.
// bf16 MFMA 16x16x32 end-to-end. Each wave computes its own 16 q/k/v dims
// (per-lane vector weight loads), stages K/V^T into disjoint regions of
// shared LDS arrays, keeps Q^T in registers. P redistributed through a
// per-wave single-buffered LDS slice (DS pipe is in-order per wave).
// Streaming softmax (no max subtraction, |score|<~2), col-sums via
// 2x shfl_xor. Final Y = sum of both waves' head-partials via LDS.
// klds rows = 80B (5x16B, odd multiple of 16 -> aligned b128 reads,
// conflict-free broadcast row walks). NO min-waves launch bound: the
// kernel needs ~100 VGPR; capping it caused 4x spill traffic in R6.
#define NB 8192

typedef __attribute__((ext_vector_type(8))) short short8;
typedef __attribute__((ext_vector_type(4))) float f32x4;

union S8U { short8 s; unsigned u[4]; uint4 v; };

static __device__ __forceinline__ unsigned pk2(float a, float b) {
    unsigned short ua = __builtin_bit_cast(unsigned short, (__bf16)a);
    unsigned short ub = __builtin_bit_cast(unsigned short, (__bf16)b);
    return (unsigned)ua | ((unsigned)ub << 16);
}

#define MFMA __builtin_amdgcn_mfma_f32_16x16x32_bf16
#define BPERM __builtin_amdgcn_ds_bpermute
// compiler-only fence: pins in-wave LDS write->read program order
#define LDSFENCE() asm volatile("" ::: "memory")

__global__ __launch_bounds__(128) void fused_attn_mfma(
    const float* __restrict__ x,
    const int*   __restrict__ aatt,
    const float* __restrict__ Wq, const float* __restrict__ bq,
    const float* __restrict__ Wk, const float* __restrict__ bk,
    const float* __restrict__ Wv, const float* __restrict__ bv,
    const float* __restrict__ Wp, const float* __restrict__ bp,
    float* __restrict__ out)
{
    __shared__ __align__(16) short klds[64][40];   // K[seq][dim], 80B rows (5120B)
    __shared__ __align__(16) short vbt[32][72];    // V^T[dim][seq], 144B rows (4608B)
    __shared__ __align__(16) short psl[2][16][40]; // per-wave P slice (2560B)

    const int tid  = threadIdx.x;
    const int w    = tid >> 6;          // wave: heads {2w, 2w+1}, dims 16w..16w+15
    const int lane = tid & 63;
    const int q4   = lane >> 4;
    const int l15  = lane & 15;
    const int b    = blockIdx.x;

    const int aab      = aatt[b];
    const unsigned bmask = (q4 == 0) ? 0xFFFFFFFFu : 0u;

    // allowed(j) == j <= max(i, aab-1); j = (compile-time C) + q4*4
    int cmpv[4];
#pragma unroll
    for (int it = 0; it < 4; ++it) cmpv[it] = max(l15 + 16*it, aab - 1) - q4*4;

    // ---- X fragments: row = tile*16+l15, k = q4*8+e ----
    short8 xa[4];
    const float* xb = x + (size_t)b * 64 * 32;
#pragma unroll
    for (int nt = 0; nt < 4; ++nt) {
        const float* p = xb + (nt*16 + l15)*32 + q4*8;
        float4 u0 = *(const float4*)p;
        float4 u1 = *(const float4*)(p + 4);
        S8U t;
        t.u[0] = pk2(u0.x, u0.y); t.u[1] = pk2(u0.z, u0.w);
        t.u[2] = pk2(u1.x, u1.y); t.u[3] = pk2(u1.z, u1.w);
        xa[nt] = t.s;
    }

    auto wrow = [&](const float* W, int row) -> short8 {
        const float* p = W + row*32 + q4*8;
        float4 u0 = *(const float4*)p;
        float4 u1 = *(const float4*)(p + 4);
        S8U t;
        t.u[0] = pk2(u0.x, u0.y); t.u[1] = pk2(u0.z, u0.w);
        t.u[2] = pk2(u1.x, u1.y); t.u[3] = pk2(u1.z, u1.w);
        return t.s;
    };

    const float escale = 0.35355339059327373f * 1.4426950408889634f; // 1/sqrt(8)*log2(e)

    // ---- Q^T (this wave's 16 dims) -> registers, bias+scale in f32 ----
    unsigned qpk01[4], qpk23[4];
    {
        short8 wa = wrow(Wq, 16*w + l15);
        float4 b4 = *(const float4*)(bq + 16*w + q4*4);
#pragma unroll
        for (int nt = 0; nt < 4; ++nt) {
            f32x4 acc = {0.f,0.f,0.f,0.f};
            acc = MFMA(wa, xa[nt], acc, 0,0,0);
            qpk01[nt] = pk2((acc[0]+b4.x)*escale, (acc[1]+b4.y)*escale);
            qpk23[nt] = pk2((acc[2]+b4.z)*escale, (acc[3]+b4.w)*escale);
        }
    }
    // ---- K^T (this wave's 16 dims) -> klds cols 16w.. ----
    {
        short8 wa = wrow(Wk, 16*w + l15);
        float4 b4 = *(const float4*)(bk + 16*w + q4*4);
#pragma unroll
        for (int nt = 0; nt < 4; ++nt) {
            f32x4 acc = {0.f,0.f,0.f,0.f};
            acc = MFMA(wa, xa[nt], acc, 0,0,0);
            uint2 w2;
            w2.x = pk2(acc[0]+b4.x, acc[1]+b4.y);
            w2.y = pk2(acc[2]+b4.z, acc[3]+b4.w);
            *(uint2*)&klds[nt*16 + l15][16*w + q4*4] = w2;
        }
    }
    // ---- V (this wave's 16 dims) -> vbt rows 16w.. (V transposed) ----
    {
        short8 wv = wrow(Wv, 16*w + l15);
        const float bvv = bv[16*w + l15];
#pragma unroll
        for (int mt = 0; mt < 4; ++mt) {
            f32x4 acc = {0.f,0.f,0.f,0.f};
            acc = MFMA(xa[mt], wv, acc, 0,0,0);
            uint2 w2;
            w2.x = pk2(acc[0]+bvv, acc[1]+bvv);
            w2.y = pk2(acc[2]+bvv, acc[3]+bvv);
            *(uint2*)&vbt[16*w + l15][mt*16 + q4*4] = w2;
        }
    }
    LDSFENCE();   // wave reads only its own staging regions -> no barrier

    // ---- head loop (2 heads per wave) ----
    f32x4 yacc[4][2];
#pragma unroll
    for (int mt = 0; mt < 4; ++mt)
#pragma unroll
        for (int nt = 0; nt < 2; ++nt) yacc[mt][nt] = (f32x4){0.f,0.f,0.f,0.f};

#pragma unroll
    for (int hl = 0; hl < 2; ++hl) {
        const int idxA = (32*hl + l15) * 4;        // lane (q4=2hl,   l15)
        const int idxB = idxA + 64;                // lane (q4=2hl+1, l15)

        // Q B-frags: zero k>=8 via bmask
        short8 sqb[4];
#pragma unroll
        for (int it = 0; it < 4; ++it) {
            S8U t;
            t.u[0] = (unsigned)BPERM(idxA, (int)qpk01[it]) & bmask;
            t.u[1] = (unsigned)BPERM(idxA, (int)qpk23[it]) & bmask;
            t.u[2] = (unsigned)BPERM(idxB, (int)qpk01[it]) & bmask;
            t.u[3] = (unsigned)BPERM(idxB, (int)qpk23[it]) & bmask;
            sqb[it] = t.s;
        }
        // Wp head-slice B-frags (head h = 2w+hl), zero k>=8
        short8 wpb[2];
#pragma unroll
        for (int nt = 0; nt < 2; ++nt) {
            const float* p = Wp + (nt*16 + l15)*32 + 16*w + 8*hl;
            float4 u0 = *(const float4*)p;
            float4 u1 = *(const float4*)(p + 4);
            S8U t;
            t.u[0] = pk2(u0.x,u0.y) & bmask;
            t.u[1] = pk2(u0.z,u0.w) & bmask;
            t.u[2] = pk2(u1.x,u1.y) & bmask;
            t.u[3] = pk2(u1.z,u1.w) & bmask;
            wpb[nt] = t.s;
        }

        float csum[4] = {0.f,0.f,0.f,0.f};
        f32x4 oacch[4];
#pragma unroll
        for (int it = 0; it < 4; ++it) oacch[it] = (f32x4){0.f,0.f,0.f,0.f};

#pragma unroll
        for (int jb = 0; jb < 2; ++jb) {
            // K A-frags: q4-uniform broadcast rows (16B-aligned, 80B stride)
            short8 ska[2];
#pragma unroll
            for (int jt = 0; jt < 2; ++jt) {
                S8U t; t.v = *(const uint4*)&klds[jb*32 + jt*16 + l15][16*w + 8*hl];
                ska[jt] = t.s;
            }
            // V^T A-frag for this head & j-half
            S8U av; av.v = *(const uint4*)&vbt[16*w + 8*hl + (l15 & 7)][jb*32 + q4*8];

#pragma unroll
            for (int it = 0; it < 4; ++it) {
#pragma unroll
                for (int jt = 0; jt < 2; ++jt) {
                    f32x4 sacc = {0.f,0.f,0.f,0.f};
                    sacc = MFMA(ska[jt], sqb[it], sacc, 0,0,0);
                    float e[4];
#pragma unroll
                    for (int r = 0; r < 4; ++r) {
                        float ee = __builtin_amdgcn_exp2f(sacc[r]);
                        e[r] = (jb*32 + jt*16 + r <= cmpv[it]) ? ee : 0.0f;
                    }
                    csum[it] += (e[0]+e[1]) + (e[2]+e[3]);
                    uint2 pw; pw.x = pk2(e[0], e[1]); pw.y = pk2(e[2], e[3]);
                    *(uint2*)&psl[w][l15][jt*16 + q4*4] = pw;
                }
                LDSFENCE();
                S8U pb; pb.v = *(const uint4*)&psl[w][l15][q4*8];
                oacch[it] = MFMA(av.s, pb.s, oacch[it], 0,0,0);
                LDSFENCE();
            }
        }

        // column sums + normalize
        float inv[4];
#pragma unroll
        for (int it = 0; it < 4; ++it) {
            float a = csum[it];
            a += __shfl_xor(a, 16, 64);
            a += __shfl_xor(a, 32, 64);
            inv[it] = 1.0f / a;
        }
        unsigned opk01[4], opk23[4];
#pragma unroll
        for (int it = 0; it < 4; ++it) {
            opk01[it] = pk2(oacch[it][0]*inv[it], oacch[it][1]*inv[it]);
            opk23[it] = pk2(oacch[it][2]*inv[it], oacch[it][3]*inv[it]);
        }
        // out-projection partial: Y += O_head @ Wp_head^T
        const int idx0 = l15 * 4;
        const int idx1 = idx0 + 64;
#pragma unroll
        for (int mtile = 0; mtile < 4; ++mtile) {
            S8U t;
            t.u[0] = (unsigned)BPERM(idx0, (int)opk01[mtile]);
            t.u[1] = (unsigned)BPERM(idx0, (int)opk23[mtile]);
            t.u[2] = (unsigned)BPERM(idx1, (int)opk01[mtile]);
            t.u[3] = (unsigned)BPERM(idx1, (int)opk23[mtile]);
#pragma unroll
            for (int nt = 0; nt < 2; ++nt)
                yacc[mtile][nt] = MFMA(t.s, wpb[nt], yacc[mtile][nt], 0,0,0);
        }
    }

    // ---- cross-wave reduction of Y partials through reclaimed LDS ----
    __syncthreads();   // all klds/vbt reads complete
    float* scrA = (float*)&klds[0][0];   // wave0 writes here (4096B used, 5120 avail)
    float* scrB = (float*)&vbt[0][0];    // wave1 writes here (4096B used, 4608 avail)
    if (w == 0) {
#pragma unroll
        for (int mtl = 0; mtl < 2; ++mtl)
#pragma unroll
            for (int nt = 0; nt < 2; ++nt)
                *(f32x4*)&scrA[((mtl*2 + nt)*64 + lane)*4] = yacc[2 + mtl][nt];
    } else {
#pragma unroll
        for (int mtl = 0; mtl < 2; ++mtl)
#pragma unroll
            for (int nt = 0; nt < 2; ++nt)
                *(f32x4*)&scrB[((mtl*2 + nt)*64 + lane)*4] = yacc[mtl][nt];
    }
    __syncthreads();

    const float bpv[2] = { bp[l15], bp[16 + l15] };
    float* ob = out + (size_t)b * 64 * 32;
    if (w == 0) {      // rows 0..31  (mtiles 0,1), partner partial from scrB
#pragma unroll
        for (int mtl = 0; mtl < 2; ++mtl)
#pragma unroll
            for (int nt = 0; nt < 2; ++nt) {
                f32x4 o = *(const f32x4*)&scrB[((mtl*2 + nt)*64 + lane)*4];
#pragma unroll
                for (int r = 0; r < 4; ++r)
                    ob[(mtl*16 + q4*4 + r)*32 + nt*16 + l15] =
                        yacc[mtl][nt][r] + o[r] + bpv[nt];
            }
    } else {           // rows 32..63 (mtiles 2,3), partner partial from scrA
#pragma unroll
        for (int mtl = 0; mtl < 2; ++mtl)
#pragma unroll
            for (int nt = 0; nt < 2; ++nt) {
                f32x4 o = *(const f32x4*)&scrA[((mtl*2 + nt)*64 + lane)*4];
#pragma unroll
                for (int r = 0; r < 4; ++r)
                    ob[((2 + mtl)*16 + q4*4 + r)*32 + nt*16 + l15] =
                        yacc[2 + mtl][nt][r] + o[r] + bpv[nt];
            }
    }
}

extern "C" void kernel_launch(void* const* d_in, const int* in_sizes, int n_in,
                              void* d_out, int out_size, void* d_ws, size_t ws_size,
                              hipStream_t stream) {
    const float* x  = (const float*)d_in[0];
    const int*   aa = (const int*)d_in[1];
    const float* Wq = (const float*)d_in[2];
    const float* bq = (const float*)d_in[3];
    const float* Wk = (const float*)d_in[4];
    const float* bk = (const float*)d_in[5];
    const float* Wv = (const float*)d_in[6];
    const float* bv = (const float*)d_in[7];
    const float* Wp = (const float*)d_in[8];
    const float* bp = (const float*)d_in[9];
    float* out = (float*)d_out;

    dim3 grid(NB), block(128);
    hipLaunchKernelGGL(fused_attn_mfma, grid, block, 0, stream,
                       x, aa, Wq, bq, Wk, bk, Wv, bv, Wp, bp, out);
}

// Round 8
// 62.326 us; speedup vs baseline: 1.5476x; 1.2851x over previous
//
#include <hip/hip_runtime.h>
#include <cstdint>
#include <cstddef>

// Fused prefix-LM self-attention, B=8192, S=64, D=32, H=4, DH=8.
// Block = 128 thr = 2 waves = 1 batch; wave w owns heads {2w,2w+1}.
// bf16 MFMA 16x16x32 end-to-end. Each wave computes its own 16 q/k/v dims
// (per-lane vector weight loads), stages K/V^T into disjoint regions of
// shared LDS arrays, keeps Q^T in registers. P redistributed through a
// per-wave single-buffered LDS slice (DS pipe is in-order per wave).
// Streaming softmax (no max subtraction, |score|<~2), col-sums via
// 2x shfl_xor. R8 change: out-projection DEFERRED to a tail phase --
// during the head loop we save only packed O-frags (8 dwords/head), so
// the 32-reg yacc accumulator + wpb are live only in the tail. This
// drops max-live registers by ~1 HW granule (unified VGPR/AGPR file)
// to raise waves/SIMD. launch_bounds(128,4): cap 128 regs >> ~100 need.
#define NB 8192

typedef __attribute__((ext_vector_type(8))) short short8;
typedef __attribute__((ext_vector_type(4))) float f32x4;

union S8U { short8 s; unsigned u[4]; uint4 v; };

static __device__ __forceinline__ unsigned pk2(float a, float b) {
    unsigned short ua = __builtin_bit_cast(unsigned short, (__bf16)a);
    unsigned short ub = __builtin_bit_cast(unsigned short, (__bf16)b);
    return (unsigned)ua | ((unsigned)ub << 16);
}

#define MFMA __builtin_amdgcn_mfma_f32_16x16x32_bf16
#define BPERM __builtin_amdgcn_ds_bpermute
// compiler-only fence: pins in-wave LDS write->read program order
#define LDSFENCE() asm volatile("" ::: "memory")

__global__ __launch_bounds__(128, 4) void fused_attn_mfma(
    const float* __restrict__ x,
    const int*   __restrict__ aatt,
    const float* __restrict__ Wq, const float* __restrict__ bq,
    const float* __restrict__ Wk, const float* __restrict__ bk,
    const float* __restrict__ Wv, const float* __restrict__ bv,
    const float* __restrict__ Wp, const float* __restrict__ bp,
    float* __restrict__ out)
{
    __shared__ __align__(16) short klds[64][40];   // K[seq][dim], 80B rows (5120B)
    __shared__ __align__(16) short vbt[32][72];    // V^T[dim][seq], 144B rows (4608B)
    __shared__ __align__(16) short psl[2][16][40]; // per-wave P slice (2560B)

    const int tid  = threadIdx.x;
    const int w    = tid >> 6;          // wave: heads {2w, 2w+1}, dims 16w..16w+15
    const int lane = tid & 63;
    const int q4   = lane >> 4;
    const int l15  = lane & 15;
    const int b    = blockIdx.x;

    const int aab      = aatt[b];
    const unsigned bmask = (q4 == 0) ? 0xFFFFFFFFu : 0u;

    // allowed(j) == j <= max(i, aab-1); j = (compile-time C) + q4*4
    int cmpv[4];
#pragma unroll
    for (int it = 0; it < 4; ++it) cmpv[it] = max(l15 + 16*it, aab - 1) - q4*4;

    // ---- X fragments: row = tile*16+l15, k = q4*8+e ----
    short8 xa[4];
    const float* xb = x + (size_t)b * 64 * 32;
#pragma unroll
    for (int nt = 0; nt < 4; ++nt) {
        const float* p = xb + (nt*16 + l15)*32 + q4*8;
        float4 u0 = *(const float4*)p;
        float4 u1 = *(const float4*)(p + 4);
        S8U t;
        t.u[0] = pk2(u0.x, u0.y); t.u[1] = pk2(u0.z, u0.w);
        t.u[2] = pk2(u1.x, u1.y); t.u[3] = pk2(u1.z, u1.w);
        xa[nt] = t.s;
    }

    auto wrow = [&](const float* W, int row) -> short8 {
        const float* p = W + row*32 + q4*8;
        float4 u0 = *(const float4*)p;
        float4 u1 = *(const float4*)(p + 4);
        S8U t;
        t.u[0] = pk2(u0.x, u0.y); t.u[1] = pk2(u0.z, u0.w);
        t.u[2] = pk2(u1.x, u1.y); t.u[3] = pk2(u1.z, u1.w);
        return t.s;
    };

    const float escale = 0.35355339059327373f * 1.4426950408889634f; // 1/sqrt(8)*log2(e)

    // ---- Q^T (this wave's 16 dims) -> registers, bias+scale in f32 ----
    unsigned qpk01[4], qpk23[4];
    {
        short8 wa = wrow(Wq, 16*w + l15);
        float4 b4 = *(const float4*)(bq + 16*w + q4*4);
#pragma unroll
        for (int nt = 0; nt < 4; ++nt) {
            f32x4 acc = {0.f,0.f,0.f,0.f};
            acc = MFMA(wa, xa[nt], acc, 0,0,0);
            qpk01[nt] = pk2((acc[0]+b4.x)*escale, (acc[1]+b4.y)*escale);
            qpk23[nt] = pk2((acc[2]+b4.z)*escale, (acc[3]+b4.w)*escale);
        }
    }
    // ---- K^T (this wave's 16 dims) -> klds cols 16w.. ----
    {
        short8 wa = wrow(Wk, 16*w + l15);
        float4 b4 = *(const float4*)(bk + 16*w + q4*4);
#pragma unroll
        for (int nt = 0; nt < 4; ++nt) {
            f32x4 acc = {0.f,0.f,0.f,0.f};
            acc = MFMA(wa, xa[nt], acc, 0,0,0);
            uint2 w2;
            w2.x = pk2(acc[0]+b4.x, acc[1]+b4.y);
            w2.y = pk2(acc[2]+b4.z, acc[3]+b4.w);
            *(uint2*)&klds[nt*16 + l15][16*w + q4*4] = w2;
        }
    }
    // ---- V (this wave's 16 dims) -> vbt rows 16w.. (V transposed) ----
    {
        short8 wv = wrow(Wv, 16*w + l15);
        const float bvv = bv[16*w + l15];
#pragma unroll
        for (int mt = 0; mt < 4; ++mt) {
            f32x4 acc = {0.f,0.f,0.f,0.f};
            acc = MFMA(xa[mt], wv, acc, 0,0,0);
            uint2 w2;
            w2.x = pk2(acc[0]+bvv, acc[1]+bvv);
            w2.y = pk2(acc[2]+bvv, acc[3]+bvv);
            *(uint2*)&vbt[16*w + l15][mt*16 + q4*4] = w2;
        }
    }
    LDSFENCE();   // wave reads only its own staging regions -> no barrier

    // ---- head loop (2 heads per wave): produce packed O-frags only ----
    unsigned opk01s[2][4], opk23s[2][4];

#pragma unroll
    for (int hl = 0; hl < 2; ++hl) {
        const int idxA = (32*hl + l15) * 4;        // lane (q4=2hl,   l15)
        const int idxB = idxA + 64;                // lane (q4=2hl+1, l15)

        // Q B-frags: zero k>=8 via bmask
        short8 sqb[4];
#pragma unroll
        for (int it = 0; it < 4; ++it) {
            S8U t;
            t.u[0] = (unsigned)BPERM(idxA, (int)qpk01[it]) & bmask;
            t.u[1] = (unsigned)BPERM(idxA, (int)qpk23[it]) & bmask;
            t.u[2] = (unsigned)BPERM(idxB, (int)qpk01[it]) & bmask;
            t.u[3] = (unsigned)BPERM(idxB, (int)qpk23[it]) & bmask;
            sqb[it] = t.s;
        }

        float csum[4] = {0.f,0.f,0.f,0.f};
        f32x4 oacch[4];
#pragma unroll
        for (int it = 0; it < 4; ++it) oacch[it] = (f32x4){0.f,0.f,0.f,0.f};

#pragma unroll
        for (int jb = 0; jb < 2; ++jb) {
            // K A-frags: q4-uniform broadcast rows (16B-aligned, 80B stride)
            short8 ska[2];
#pragma unroll
            for (int jt = 0; jt < 2; ++jt) {
                S8U t; t.v = *(const uint4*)&klds[jb*32 + jt*16 + l15][16*w + 8*hl];
                ska[jt] = t.s;
            }
            // V^T A-frag for this head & j-half
            S8U av; av.v = *(const uint4*)&vbt[16*w + 8*hl + (l15 & 7)][jb*32 + q4*8];

#pragma unroll
            for (int it = 0; it < 4; ++it) {
#pragma unroll
                for (int jt = 0; jt < 2; ++jt) {
                    f32x4 sacc = {0.f,0.f,0.f,0.f};
                    sacc = MFMA(ska[jt], sqb[it], sacc, 0,0,0);
                    float e[4];
#pragma unroll
                    for (int r = 0; r < 4; ++r) {
                        float ee = __builtin_amdgcn_exp2f(sacc[r]);
                        e[r] = (jb*32 + jt*16 + r <= cmpv[it]) ? ee : 0.0f;
                    }
                    csum[it] += (e[0]+e[1]) + (e[2]+e[3]);
                    uint2 pw; pw.x = pk2(e[0], e[1]); pw.y = pk2(e[2], e[3]);
                    *(uint2*)&psl[w][l15][jt*16 + q4*4] = pw;
                }
                LDSFENCE();
                S8U pb; pb.v = *(const uint4*)&psl[w][l15][q4*8];
                oacch[it] = MFMA(av.s, pb.s, oacch[it], 0,0,0);
                LDSFENCE();
            }
        }

        // column sums + normalize -> save packed O-frags (8 dwords/head)
        float inv[4];
#pragma unroll
        for (int it = 0; it < 4; ++it) {
            float a = csum[it];
            a += __shfl_xor(a, 16, 64);
            a += __shfl_xor(a, 32, 64);
            inv[it] = 1.0f / a;
        }
#pragma unroll
        for (int it = 0; it < 4; ++it) {
            opk01s[hl][it] = pk2(oacch[it][0]*inv[it], oacch[it][1]*inv[it]);
            opk23s[hl][it] = pk2(oacch[it][2]*inv[it], oacch[it][3]*inv[it]);
        }
    }

    // ---- tail: out-projection Y = sum_h O_h @ Wp_h^T ----
    f32x4 yacc[4][2];
#pragma unroll
    for (int mt = 0; mt < 4; ++mt)
#pragma unroll
        for (int nt = 0; nt < 2; ++nt) yacc[mt][nt] = (f32x4){0.f,0.f,0.f,0.f};

    const int idx0 = l15 * 4;
    const int idx1 = idx0 + 64;
#pragma unroll
    for (int hl = 0; hl < 2; ++hl) {
        // Wp head-slice B-frags (head h = 2w+hl), zero k>=8
        short8 wpb[2];
#pragma unroll
        for (int nt = 0; nt < 2; ++nt) {
            const float* p = Wp + (nt*16 + l15)*32 + 16*w + 8*hl;
            float4 u0 = *(const float4*)p;
            float4 u1 = *(const float4*)(p + 4);
            S8U t;
            t.u[0] = pk2(u0.x,u0.y) & bmask;
            t.u[1] = pk2(u0.z,u0.w) & bmask;
            t.u[2] = pk2(u1.x,u1.y) & bmask;
            t.u[3] = pk2(u1.z,u1.w) & bmask;
            wpb[nt] = t.s;
        }
#pragma unroll
        for (int mtile = 0; mtile < 4; ++mtile) {
            S8U t;
            t.u[0] = (unsigned)BPERM(idx0, (int)opk01s[hl][mtile]);
            t.u[1] = (unsigned)BPERM(idx0, (int)opk23s[hl][mtile]);
            t.u[2] = (unsigned)BPERM(idx1, (int)opk01s[hl][mtile]);
            t.u[3] = (unsigned)BPERM(idx1, (int)opk23s[hl][mtile]);
#pragma unroll
            for (int nt = 0; nt < 2; ++nt)
                yacc[mtile][nt] = MFMA(t.s, wpb[nt], yacc[mtile][nt], 0,0,0);
        }
    }

    // ---- cross-wave reduction of Y partials through reclaimed LDS ----
    __syncthreads();   // all klds/vbt reads complete
    float* scrA = (float*)&klds[0][0];   // wave0 writes here (4096B used, 5120 avail)
    float* scrB = (float*)&vbt[0][0];    // wave1 writes here (4096B used, 4608 avail)
    if (w == 0) {
#pragma unroll
        for (int mtl = 0; mtl < 2; ++mtl)
#pragma unroll
            for (int nt = 0; nt < 2; ++nt)
                *(f32x4*)&scrA[((mtl*2 + nt)*64 + lane)*4] = yacc[2 + mtl][nt];
    } else {
#pragma unroll
        for (int mtl = 0; mtl < 2; ++mtl)
#pragma unroll
            for (int nt = 0; nt < 2; ++nt)
                *(f32x4*)&scrB[((mtl*2 + nt)*64 + lane)*4] = yacc[mtl][nt];
    }
    __syncthreads();

    const float bpv[2] = { bp[l15], bp[16 + l15] };
    float* ob = out + (size_t)b * 64 * 32;
    if (w == 0) {      // rows 0..31  (mtiles 0,1), partner partial from scrB
#pragma unroll
        for (int mtl = 0; mtl < 2; ++mtl)
#pragma unroll
            for (int nt = 0; nt < 2; ++nt) {
                f32x4 o = *(const f32x4*)&scrB[((mtl*2 + nt)*64 + lane)*4];
#pragma unroll
                for (int r = 0; r < 4; ++r)
                    ob[(mtl*16 + q4*4 + r)*32 + nt*16 + l15] =
                        yacc[mtl][nt][r] + o[r] + bpv[nt];
            }
    } else {           // rows 32..63 (mtiles 2,3), partner partial from scrA
#pragma unroll
        for (int mtl = 0; mtl < 2; ++mtl)
#pragma unroll
            for (int nt = 0; nt < 2; ++nt) {
                f32x4 o = *(const f32x4*)&scrA[((mtl*2 + nt)*64 + lane)*4];
#pragma unroll
                for (int r = 0; r < 4; ++r)
                    ob[((2 + mtl)*16 + q4*4 + r)*32 + nt*16 + l15] =
                        yacc[2 + mtl][nt][r] + o[r] + bpv[nt];
            }
    }
}

extern "C" void kernel_launch(void* const* d_in, const int* in_sizes, int n_in,
                              void* d_out, int out_size, void* d_ws, size_t ws_size,
                              hipStream_t stream) {
    const float* x  = (const float*)d_in[0];
    const int*   aa = (const int*)d_in[1];
    const float* Wq = (const float*)d_in[2];
    const float* bq = (const float*)d_in[3];
    const float* Wk = (const float*)d_in[4];
    const float* bk = (const float*)d_in[5];
    const float* Wv = (const float*)d_in[6];
    const float* bv = (const float*)d_in[7];
    const float* Wp = (const float*)d_in[8];
    const float* bp = (const float*)d_in[9];
    float* out = (float*)d_out;

    dim3 grid(NB), block(128);
    hipLaunchKernelGGL(fused_attn_mfma, grid, block, 0, stream,
                       x, aa, Wq, bq, Wk, bk, Wv, bv, Wp, bp, out);
}